// Round 7
// baseline (237.256 us; speedup 1.0000x reference)
//
#include <hip/hip_runtime.h>
#include <hip/hip_bf16.h>

#define HH 128
#define EE 256
#define KK 4
#define RR 8
#define LL 2
#define BB 2
#define SS 1024
#define BT (BB*SS)      // 2048 tokens total
#define NJ (RR+2*HH)    // 264 dbc rows
#define GG 16           // scan chunks per sequence
#define CH (SS/GG)      // 64 timesteps per chunk
#define EPS 1e-5f
#define LOG2E 1.44269504088896f

__device__ __forceinline__ float silu_f(float v) {
    return v / (1.0f + __expf(-v));
}

// ---------------- K0: Wdt = pl_w[:, :8] @ dt_w ; bdt = pl_b[:8]@dt_w + dt_b --
__global__ __launch_bounds__(256) void k_wdt(
    const float* __restrict__ plw, const float* __restrict__ plb,
    const float* __restrict__ dtw, const float* __restrict__ dtb,
    float* __restrict__ Wdt, float* __restrict__ bdt)
{
    const int l = blockIdx.x >> 2, q = blockIdx.x & 3;
    const int j = threadIdx.x;
    const float* dtwl = dtw + (size_t)l * RR * EE;
    const float* plwl = plw + (size_t)l * EE * NJ;
    float wr[RR];
    #pragma unroll
    for (int r = 0; r < RR; r++) wr[r] = dtwl[r * EE + j];
    float* Wl = Wdt + (size_t)l * EE * EE;
    for (int e = q * 64; e < q * 64 + 64; e++) {
        float a = 0.0f;
        #pragma unroll
        for (int r = 0; r < RR; r++) a += plwl[(size_t)e * NJ + r] * wr[r];
        Wl[(size_t)e * EE + j] = a;
    }
    if (q == 0) {
        float a = dtb[l * EE + j];
        #pragma unroll
        for (int r = 0; r < RR; r++) a += plb[l * NJ + r] * wr[r];
        bdt[l * EE + j] = a;
    }
}

// ---------------- K1: front half of a layer ----------------------------------
// rmsnorm + in_proj + conv+silu + B/C-proj + delta-proj, 8-token tiles,
// grid 256, block 512. Lookback (3 tokens) recomputed locally.
__global__ __launch_bounds__(512) void k_front(
    const float* __restrict__ resin, const float* __restrict__ inw,
    const float* __restrict__ inb, const float* __restrict__ nw,
    const float* __restrict__ cw, const float* __restrict__ cb,
    const float* __restrict__ plw, const float* __restrict__ plb,
    const float* __restrict__ Wdt, const float* __restrict__ bdt,
    float* __restrict__ zbuf, float* __restrict__ xcT,
    float* __restrict__ BC4, float* __restrict__ deltaT,
    float* __restrict__ sT)
{
    __shared__ float xn[11][132];    // normalized tokens (lookback + 8)
    __shared__ float xci[11][256];   // in_proj xc columns (conv input)
    __shared__ float xcb[8][256];    // conv output
    const int bt0 = blockIdx.x * 8;
    const int tid = threadIdx.x;
    const int lb = ((bt0 & (SS - 1)) == 0) ? 0 : 3;
    // Phase A: rmsnorm for tokens bt0-lb .. bt0+7
    {
        const int tt = tid >> 5, lane = tid & 31;
        if (tt < lb + 8) {
            const int bt = bt0 - lb + tt;
            const float4 xv = *(const float4*)(resin + (size_t)bt * HH + lane * 4);
            float ss = xv.x*xv.x + xv.y*xv.y + xv.z*xv.z + xv.w*xv.w;
            ss += __shfl_xor(ss, 16); ss += __shfl_xor(ss, 8);
            ss += __shfl_xor(ss, 4);  ss += __shfl_xor(ss, 2);
            ss += __shfl_xor(ss, 1);
            const float rs = rsqrtf(ss * (1.0f / HH) + EPS);
            const float4 wv = *(const float4*)(nw + lane * 4);
            xn[tt][lane*4+0] = xv.x * rs * wv.x;
            xn[tt][lane*4+1] = xv.y * rs * wv.y;
            xn[tt][lane*4+2] = xv.z * rs * wv.z;
            xn[tt][lane*4+3] = xv.w * rs * wv.w;
        }
    }
    __syncthreads();
    // Phase B: in_proj. path0: xc cols (11 tokens) -> xci. path1: z cols -> zbuf.
    if (tid < 256) {
        const int j = tid;
        float acc[11];
        const float bj = inb[j];
        #pragma unroll
        for (int t = 0; t < 11; t++) acc[t] = bj;
        float w0n = inw[0*512 + j], w1n = inw[1*512 + j];
        float w2n = inw[2*512 + j], w3n = inw[3*512 + j];
        for (int k4 = 0; k4 < 32; k4++) {
            const float w0 = w0n, w1 = w1n, w2 = w2n, w3 = w3n;
            if (k4 < 31) {
                const int k = (k4 + 1) * 4;
                w0n = inw[(k+0)*512 + j]; w1n = inw[(k+1)*512 + j];
                w2n = inw[(k+2)*512 + j]; w3n = inw[(k+3)*512 + j];
            }
            const int k = k4 * 4;
            #pragma unroll
            for (int t = 0; t < 11; t++) {
                const float4 xv = *(const float4*)(&xn[t][k]);
                acc[t] += w0*xv.x + w1*xv.y + w2*xv.z + w3*xv.w;
            }
        }
        #pragma unroll
        for (int t = 0; t < 11; t++)
            if (t < lb + 8) xci[t][j] = acc[t];
    } else {
        const int j = tid - 256;
        float acc[8];
        const float bj = inb[256 + j];
        #pragma unroll
        for (int t = 0; t < 8; t++) acc[t] = bj;
        float w0n = inw[0*512 + 256 + j], w1n = inw[1*512 + 256 + j];
        float w2n = inw[2*512 + 256 + j], w3n = inw[3*512 + 256 + j];
        for (int k4 = 0; k4 < 32; k4++) {
            const float w0 = w0n, w1 = w1n, w2 = w2n, w3 = w3n;
            if (k4 < 31) {
                const int k = (k4 + 1) * 4;
                w0n = inw[(k+0)*512 + 256 + j]; w1n = inw[(k+1)*512 + 256 + j];
                w2n = inw[(k+2)*512 + 256 + j]; w3n = inw[(k+3)*512 + 256 + j];
            }
            const int k = k4 * 4;
            #pragma unroll
            for (int t = 0; t < 8; t++) {
                const float4 xv = *(const float4*)(&xn[lb + t][k]);
                acc[t] += w0*xv.x + w1*xv.y + w2*xv.z + w3*xv.w;
            }
        }
        #pragma unroll
        for (int t = 0; t < 8; t++)
            zbuf[(size_t)(bt0 + t) * 256 + j] = acc[t];
    }
    __syncthreads();
    // Phase C: conv + silu. (e, hf): 4 tokens each.
    {
        const int e = tid & 255, hf = tid >> 8;
        const float w0 = cw[e*4+0], w1 = cw[e*4+1], w2 = cw[e*4+2], w3 = cw[e*4+3];
        const float bias = cb[e];
        float xcv[4];
        #pragma unroll
        for (int i = 0; i < 4; i++) {
            const int m = lb + hf * 4 + i;
            const float a0  = xci[m][e];
            const float am1 = (m >= 1) ? xci[m-1][e] : 0.0f;
            const float am2 = (m >= 2) ? xci[m-2][e] : 0.0f;
            const float am3 = (m >= 3) ? xci[m-3][e] : 0.0f;
            const float v = bias + w3*a0 + w2*am1 + w1*am2 + w0*am3;
            const float o = silu_f(v);
            xcv[i] = o;
            xcb[hf*4 + i][e] = o;
        }
        *(float4*)(xcT + (size_t)e * BT + bt0 + hf * 4) =
            make_float4(xcv[0], xcv[1], xcv[2], xcv[3]);
    }
    __syncthreads();
    // Phase D: projections from xcb. path0: B/C -> BC4. path1: delta -> deltaT,sT.
    const int j = tid & 255, path = tid >> 8;
    if (path == 0) {
        const int nn = j & 127, isC = j >> 7;
        const float* wp = plw + RR + isC * HH + nn;
        float acc[8];
        const float bj = plb[RR + isC * HH + nn];
        #pragma unroll
        for (int t = 0; t < 8; t++) acc[t] = bj;
        float w0n = wp[0*NJ], w1n = wp[1*NJ], w2n = wp[2*NJ], w3n = wp[3*NJ];
        for (int e4 = 0; e4 < 64; e4++) {
            const float w0 = w0n, w1 = w1n, w2 = w2n, w3 = w3n;
            if (e4 < 63) {
                const int e = (e4 + 1) * 4;
                w0n = wp[(size_t)(e+0)*NJ]; w1n = wp[(size_t)(e+1)*NJ];
                w2n = wp[(size_t)(e+2)*NJ]; w3n = wp[(size_t)(e+3)*NJ];
            }
            const int e = e4 * 4;
            #pragma unroll
            for (int t = 0; t < 8; t++) {
                const float4 xv = *(const float4*)(&xcb[t][e]);
                acc[t] += w0*xv.x + w1*xv.y + w2*xv.z + w3*xv.w;
            }
        }
        const int tq0 = bt0 >> 2;
        float* p0 = BC4 + ((size_t)tq0 * 128 + nn) * 8 + isC * 4;
        *(float4*)p0 = make_float4(acc[0], acc[1], acc[2], acc[3]);
        float* p1 = BC4 + ((size_t)(tq0 + 1) * 128 + nn) * 8 + isC * 4;
        *(float4*)p1 = make_float4(acc[4], acc[5], acc[6], acc[7]);
    } else {
        const float* wp = Wdt + j;
        float acc[8];
        const float bj = bdt[j];
        #pragma unroll
        for (int t = 0; t < 8; t++) acc[t] = bj;
        float w0n = wp[0*EE], w1n = wp[1*EE], w2n = wp[2*EE], w3n = wp[3*EE];
        for (int e4 = 0; e4 < 64; e4++) {
            const float w0 = w0n, w1 = w1n, w2 = w2n, w3 = w3n;
            if (e4 < 63) {
                const int e = (e4 + 1) * 4;
                w0n = wp[(size_t)(e+0)*EE]; w1n = wp[(size_t)(e+1)*EE];
                w2n = wp[(size_t)(e+2)*EE]; w3n = wp[(size_t)(e+3)*EE];
            }
            const int e = e4 * 4;
            #pragma unroll
            for (int t = 0; t < 8; t++) {
                const float4 xv = *(const float4*)(&xcb[t][e]);
                acc[t] += w0*xv.x + w1*xv.y + w2*xv.z + w3*xv.w;
            }
        }
        float spv[8], sv[8];
        #pragma unroll
        for (int t = 0; t < 8; t++) {
            const float d = acc[t];
            const float sp = (d > 15.0f) ? d : log1pf(__expf(d));
            spv[t] = sp;
            sv[t] = sp * xcb[t][j];
        }
        float* drp = deltaT + (size_t)j * BT + bt0;
        *(float4*)(drp)     = make_float4(spv[0], spv[1], spv[2], spv[3]);
        *(float4*)(drp + 4) = make_float4(spv[4], spv[5], spv[6], spv[7]);
        float* srp = sT + (size_t)j * BT + bt0;
        *(float4*)(srp)     = make_float4(sv[0], sv[1], sv[2], sv[3]);
        *(float4*)(srp + 4) = make_float4(sv[4], sv[5], sv[6], sv[7]);
    }
}

// ---------------- K3: chunk-local scan, 4 e's per block ----------------------
// grid = B*GG*(EE/4) = 2048, block = 128 (n). XCD-swizzled.
__global__ __launch_bounds__(128, 4) void k_scan_local(
    const float* __restrict__ BC4, const float* __restrict__ deltaT,
    const float* __restrict__ sT, const float* __restrict__ Alog,
    float* __restrict__ yT, float* __restrict__ hchain,
    float* __restrict__ dsum)
{
    __shared__ float part[4][16][68];
    __shared__ float ybuf[4][CH];
    const int blk = blockIdx.x;
    const int wgid = (blk & 7) * 256 + (blk >> 3);   // bijective XCD swizzle
    const int eq = wgid & 63;
    const int r0 = wgid >> 6;       // 0..31 = (b,g)
    const int b = r0 >> 4;
    const int g = r0 & 15;
    const int e0 = eq * 4;
    const int n = threadIdx.x;
    const int t0 = g * CH;

    float An[4], h[4], cum[4];
    #pragma unroll
    for (int ee = 0; ee < 4; ee++) {
        An[ee] = -__expf(Alog[(e0 + ee) * HH + n]) * LOG2E;
        h[ee] = 0.0f; cum[ee] = 0.0f;
    }
    const float* bc = BC4 + ((size_t)((b * 256 + g * 16) * 128 + n)) * 8;
    const float* dr[4]; const float* sr[4];
    #pragma unroll
    for (int ee = 0; ee < 4; ee++) {
        dr[ee] = deltaT + (size_t)(e0 + ee) * BT + b * SS + t0;
        sr[ee] = sT + (size_t)(e0 + ee) * BT + b * SS + t0;
    }
    float4 pB = *(const float4*)(bc);
    float4 pC = *(const float4*)(bc + 4);
    float4 pd[4], ps[4];
    #pragma unroll
    for (int ee = 0; ee < 4; ee++) {
        pd[ee] = *(const float4*)dr[ee];
        ps[ee] = *(const float4*)sr[ee];
    }
    const int tl = n >> 3, jj = n & 7;
    for (int sc = 0; sc < 4; sc++) {
        #pragma unroll
        for (int q = 0; q < 4; q++) {
            const int qq = sc * 4 + q;
            const float4 cB = pB, cC = pC;
            float4 cd[4], cs[4];
            #pragma unroll
            for (int ee = 0; ee < 4; ee++) { cd[ee] = pd[ee]; cs[ee] = ps[ee]; }
            if (qq < 15) {
                const size_t off = (size_t)(qq + 1) * 1024;
                pB = *(const float4*)(bc + off);
                pC = *(const float4*)(bc + off + 4);
                const int t = (qq + 1) * 4;
                #pragma unroll
                for (int ee = 0; ee < 4; ee++) {
                    pd[ee] = *(const float4*)(dr[ee] + t);
                    ps[ee] = *(const float4*)(sr[ee] + t);
                }
            }
            #pragma unroll
            for (int ee = 0; ee < 4; ee++) {
                float a;
                a = exp2f(cd[ee].x*An[ee]); h[ee] = a*h[ee] + cs[ee].x*cB.x;
                part[ee][q*4+0][n] = h[ee]*cC.x;
                a = exp2f(cd[ee].y*An[ee]); h[ee] = a*h[ee] + cs[ee].y*cB.y;
                part[ee][q*4+1][n] = h[ee]*cC.y;
                a = exp2f(cd[ee].z*An[ee]); h[ee] = a*h[ee] + cs[ee].z*cB.z;
                part[ee][q*4+2][n] = h[ee]*cC.z;
                a = exp2f(cd[ee].w*An[ee]); h[ee] = a*h[ee] + cs[ee].w*cB.w;
                part[ee][q*4+3][n] = h[ee]*cC.w;
                cum[ee] += (cd[ee].x + cd[ee].y) + (cd[ee].z + cd[ee].w);
            }
        }
        __syncthreads();
        #pragma unroll
        for (int ee = 0; ee < 4; ee++) {
            float s0 = 0, s1 = 0, s2 = 0, s3 = 0;
            #pragma unroll
            for (int i = 0; i < 4; i++) {
                const float4 p = *(const float4*)(&part[ee][tl][jj*16 + i*4]);
                s0 += p.x; s1 += p.y; s2 += p.z; s3 += p.w;
            }
            float r = (s0 + s1) + (s2 + s3);
            r += __shfl_xor(r, 1); r += __shfl_xor(r, 2); r += __shfl_xor(r, 4);
            if (jj == 0) ybuf[ee][sc*16 + tl] = r;
        }
        __syncthreads();
    }
    {
        const int ee = n >> 5, tt = n & 31;
        float* yp = yT + (size_t)(e0 + ee) * BT + b * SS + t0;
        yp[tt] = ybuf[ee][tt];
        yp[tt + 32] = ybuf[ee][tt + 32];
    }
    #pragma unroll
    for (int ee = 0; ee < 4; ee++)
        hchain[(size_t)(((b * EE + e0 + ee) * GG) + g) * 128 + n] = h[ee];
    if (n == 0) {
        #pragma unroll
        for (int ee = 0; ee < 4; ee++)
            dsum[(b * EE + e0 + ee) * GG + g] = cum[ee];
    }
}

// ---------------- K4: cross-chunk correction (inline combine), 4 e's ---------
// grid = B*15*(EE/4) = 1920, block = 128 (n)
__global__ __launch_bounds__(128, 4) void k_scan_fix(
    const float* __restrict__ BC4, const float* __restrict__ deltaT,
    const float* __restrict__ Alog, const float* __restrict__ hchain,
    const float* __restrict__ dsum, float* __restrict__ yT)
{
    __shared__ float part[4][16][68];
    __shared__ float ybuf[4][CH];
    const int blk = blockIdx.x;
    const int wgid = (blk & 7) * 240 + (blk >> 3);   // bijective XCD swizzle
    const int eq = wgid & 63;
    const int r0 = wgid >> 6;       // 0..29
    const int b = r0 / 15;
    const int g = 1 + (r0 % 15);
    const int e0 = eq * 4;
    const int n = threadIdx.x;
    const int t0 = g * CH;

    float An[4], w[4], D[4];
    #pragma unroll
    for (int ee = 0; ee < 4; ee++) {
        An[ee] = -__expf(Alog[(e0 + ee) * HH + n]) * LOG2E;
        w[ee] = 0.0f; D[ee] = 0.0f;
    }
    {   // inline combine: chain h_end across chunks 0..g-1
        for (int gp = 0; gp < g; gp++) {
            #pragma unroll
            for (int ee = 0; ee < 4; ee++) {
                const float he = hchain[(size_t)(((b * EE + e0 + ee) * GG) + gp) * 128 + n];
                const float ds = dsum[(b * EE + e0 + ee) * GG + gp];
                w[ee] = exp2f(An[ee] * ds) * w[ee] + he;
            }
        }
    }
    const float* bc = BC4 + ((size_t)((b * 256 + g * 16) * 128 + n)) * 8;
    const float* dr[4];
    #pragma unroll
    for (int ee = 0; ee < 4; ee++)
        dr[ee] = deltaT + (size_t)(e0 + ee) * BT + b * SS + t0;

    float4 pC = *(const float4*)(bc + 4);
    float4 pd[4];
    #pragma unroll
    for (int ee = 0; ee < 4; ee++) pd[ee] = *(const float4*)dr[ee];

    const int tl = n >> 3, jj = n & 7;
    for (int sc = 0; sc < 4; sc++) {
        #pragma unroll
        for (int q = 0; q < 4; q++) {
            const int qq = sc * 4 + q;
            const float4 cC = pC;
            float4 cd[4];
            #pragma unroll
            for (int ee = 0; ee < 4; ee++) cd[ee] = pd[ee];
            if (qq < 15) {
                const size_t off = (size_t)(qq + 1) * 1024;
                pC = *(const float4*)(bc + off + 4);
                const int t = (qq + 1) * 4;
                #pragma unroll
                for (int ee = 0; ee < 4; ee++)
                    pd[ee] = *(const float4*)(dr[ee] + t);
            }
            #pragma unroll
            for (int ee = 0; ee < 4; ee++) {
                D[ee] += cd[ee].x; part[ee][q*4+0][n] = exp2f(An[ee]*D[ee]) * w[ee] * cC.x;
                D[ee] += cd[ee].y; part[ee][q*4+1][n] = exp2f(An[ee]*D[ee]) * w[ee] * cC.y;
                D[ee] += cd[ee].z; part[ee][q*4+2][n] = exp2f(An[ee]*D[ee]) * w[ee] * cC.z;
                D[ee] += cd[ee].w; part[ee][q*4+3][n] = exp2f(An[ee]*D[ee]) * w[ee] * cC.w;
            }
        }
        __syncthreads();
        #pragma unroll
        for (int ee = 0; ee < 4; ee++) {
            float s0 = 0, s1 = 0, s2 = 0, s3 = 0;
            #pragma unroll
            for (int i = 0; i < 4; i++) {
                const float4 p = *(const float4*)(&part[ee][tl][jj*16 + i*4]);
                s0 += p.x; s1 += p.y; s2 += p.z; s3 += p.w;
            }
            float r = (s0 + s1) + (s2 + s3);
            r += __shfl_xor(r, 1); r += __shfl_xor(r, 2); r += __shfl_xor(r, 4);
            if (jj == 0) ybuf[ee][sc*16 + tl] = r;
        }
        __syncthreads();
    }
    {
        const int ee = n >> 5, tt = n & 31;
        float* yp = yT + (size_t)(e0 + ee) * BT + b * SS + t0;
        yp[tt] += ybuf[ee][tt];
        yp[tt + 32] += ybuf[ee][tt + 32];
    }
}

// ---------------- K5: gate + out_proj + residual -> xres ---------------------
__global__ __launch_bounds__(256) void k_gate(
    const float* __restrict__ yT, const float* __restrict__ xcT,
    const float* __restrict__ zbuf, const float* __restrict__ Dp,
    const float* __restrict__ ow, const float* __restrict__ ob,
    const float* __restrict__ resin, float* __restrict__ xres)
{
    __shared__ float gs[8][256];
    __shared__ float p2[8][128];
    const int bt0 = blockIdx.x * 8;
    const int tid = threadIdx.x;
    {
        const int e = tid;
        const float dp = Dp[e];
        const float* yp = yT + (size_t)e * BT + bt0;
        const float* xp = xcT + (size_t)e * BT + bt0;
        #pragma unroll
        for (int tq = 0; tq < 2; tq++) {
            const float4 y4 = *(const float4*)(yp + tq * 4);
            const float4 x4 = *(const float4*)(xp + tq * 4);
            float sk;
            sk = zbuf[(size_t)(bt0 + tq*4 + 0) * 256 + e];
            gs[tq*4+0][e] = (y4.x + dp * x4.x) * silu_f(sk);
            sk = zbuf[(size_t)(bt0 + tq*4 + 1) * 256 + e];
            gs[tq*4+1][e] = (y4.y + dp * x4.y) * silu_f(sk);
            sk = zbuf[(size_t)(bt0 + tq*4 + 2) * 256 + e];
            gs[tq*4+2][e] = (y4.z + dp * x4.z) * silu_f(sk);
            sk = zbuf[(size_t)(bt0 + tq*4 + 3) * 256 + e];
            gs[tq*4+3][e] = (y4.w + dp * x4.w) * silu_f(sk);
        }
    }
    __syncthreads();
    const int j = tid & 127;
    const int kh = tid >> 7;
    float acc[8];
    #pragma unroll
    for (int t = 0; t < 8; t++) acc[t] = 0.0f;
    const int eb = kh * 128;
    float w0n = ow[(eb+0)*HH + j], w1n = ow[(eb+1)*HH + j];
    float w2n = ow[(eb+2)*HH + j], w3n = ow[(eb+3)*HH + j];
    for (int e4 = 0; e4 < 32; e4++) {
        const float w0 = w0n, w1 = w1n, w2 = w2n, w3 = w3n;
        if (e4 < 31) {
            const int e = eb + (e4 + 1) * 4;
            w0n = ow[(e+0)*HH + j]; w1n = ow[(e+1)*HH + j];
            w2n = ow[(e+2)*HH + j]; w3n = ow[(e+3)*HH + j];
        }
        const int e = eb + e4 * 4;
        #pragma unroll
        for (int t = 0; t < 8; t++) {
            const float4 g4 = *(const float4*)(&gs[t][e]);
            acc[t] += w0*g4.x + w1*g4.y + w2*g4.z + w3*g4.w;
        }
    }
    if (kh == 1) {
        #pragma unroll
        for (int t = 0; t < 8; t++) p2[t][j] = acc[t];
    }
    __syncthreads();
    if (kh == 0) {
        const float bj = ob[j];
        #pragma unroll
        for (int t = 0; t < 8; t++) {
            const float r = acc[t] + p2[t][j] + bj
                          + resin[(size_t)(bt0 + t) * HH + j];
            xres[(size_t)(bt0 + t) * HH + j] = r;
        }
    }
}

// ---------------- K6: gate + out_proj + residual + final rmsnorm -> out ------
__global__ __launch_bounds__(256) void k_gate_final(
    const float* __restrict__ yT, const float* __restrict__ xcT,
    const float* __restrict__ zbuf, const float* __restrict__ Dp,
    const float* __restrict__ ow, const float* __restrict__ ob,
    const float* __restrict__ resin, const float* __restrict__ fw,
    float* __restrict__ out)
{
    __shared__ float gs[8][256];
    __shared__ float p2[8][132];
    const int bt0 = blockIdx.x * 8;
    const int tid = threadIdx.x;
    {
        const int e = tid;
        const float dp = Dp[e];
        const float* yp = yT + (size_t)e * BT + bt0;
        const float* xp = xcT + (size_t)e * BT + bt0;
        #pragma unroll
        for (int tq = 0; tq < 2; tq++) {
            const float4 y4 = *(const float4*)(yp + tq * 4);
            const float4 x4 = *(const float4*)(xp + tq * 4);
            float sk;
            sk = zbuf[(size_t)(bt0 + tq*4 + 0) * 256 + e];
            gs[tq*4+0][e] = (y4.x + dp * x4.x) * silu_f(sk);
            sk = zbuf[(size_t)(bt0 + tq*4 + 1) * 256 + e];
            gs[tq*4+1][e] = (y4.y + dp * x4.y) * silu_f(sk);
            sk = zbuf[(size_t)(bt0 + tq*4 + 2) * 256 + e];
            gs[tq*4+2][e] = (y4.z + dp * x4.z) * silu_f(sk);
            sk = zbuf[(size_t)(bt0 + tq*4 + 3) * 256 + e];
            gs[tq*4+3][e] = (y4.w + dp * x4.w) * silu_f(sk);
        }
    }
    __syncthreads();
    const int j = tid & 127;
    const int kh = tid >> 7;
    {
        float acc[8];
        #pragma unroll
        for (int t = 0; t < 8; t++) acc[t] = 0.0f;
        const int eb = kh * 128;
        float w0n = ow[(eb+0)*HH + j], w1n = ow[(eb+1)*HH + j];
        float w2n = ow[(eb+2)*HH + j], w3n = ow[(eb+3)*HH + j];
        for (int e4 = 0; e4 < 32; e4++) {
            const float w0 = w0n, w1 = w1n, w2 = w2n, w3 = w3n;
            if (e4 < 31) {
                const int e = eb + (e4 + 1) * 4;
                w0n = ow[(e+0)*HH + j]; w1n = ow[(e+1)*HH + j];
                w2n = ow[(e+2)*HH + j]; w3n = ow[(e+3)*HH + j];
            }
            const int e = eb + e4 * 4;
            #pragma unroll
            for (int t = 0; t < 8; t++) {
                const float4 g4 = *(const float4*)(&gs[t][e]);
                acc[t] += w0*g4.x + w1*g4.y + w2*g4.z + w3*g4.w;
            }
        }
        if (kh == 1) {
            #pragma unroll
            for (int t = 0; t < 8; t++) p2[t][j] = acc[t];
        }
        __syncthreads();
        if (kh == 0) {
            const float bj = ob[j];
            #pragma unroll
            for (int t = 0; t < 8; t++) {
                const float r = acc[t] + p2[t][j] + bj
                              + resin[(size_t)(bt0 + t) * HH + j];
                p2[t][j] = r;
            }
        }
    }
    __syncthreads();
    // final rmsnorm: 32 lanes per token
    {
        const int t = tid >> 5, lane = tid & 31;
        const float4 v = *(const float4*)(&p2[t][lane * 4]);
        float ss = v.x*v.x + v.y*v.y + v.z*v.z + v.w*v.w;
        ss += __shfl_xor(ss, 16); ss += __shfl_xor(ss, 8);
        ss += __shfl_xor(ss, 4);  ss += __shfl_xor(ss, 2);
        ss += __shfl_xor(ss, 1);
        const float rs = rsqrtf(ss * (1.0f / HH) + EPS);
        const float4 w = *(const float4*)(fw + lane * 4);
        float4 o;
        o.x = v.x * rs * w.x; o.y = v.y * rs * w.y;
        o.z = v.z * rs * w.z; o.w = v.w * rs * w.w;
        *(float4*)(out + (size_t)(bt0 + t) * HH + lane * 4) = o;
    }
}

extern "C" void kernel_launch(void* const* d_in, const int* in_sizes, int n_in,
                              void* d_out, int out_size, void* d_ws, size_t ws_size,
                              hipStream_t stream)
{
    const float* x      = (const float*)d_in[0];
    const float* in_w   = (const float*)d_in[1];
    const float* in_b   = (const float*)d_in[2];
    const float* out_w  = (const float*)d_in[3];
    const float* out_b  = (const float*)d_in[4];
    const float* pl_w   = (const float*)d_in[5];
    const float* pl_b   = (const float*)d_in[6];
    const float* dt_w   = (const float*)d_in[7];
    const float* dt_b   = (const float*)d_in[8];
    const float* conv_w = (const float*)d_in[9];
    const float* conv_b = (const float*)d_in[10];
    const float* A_log  = (const float*)d_in[11];
    const float* Dp     = (const float*)d_in[12];
    const float* norm_w = (const float*)d_in[13];
    const float* fnw    = (const float*)d_in[14];

    float* ws     = (float*)d_ws;
    float* xres   = ws;                        // 262144
    float* zbuf   = xres   + 262144;           // 524288
    float* xcT    = zbuf   + 524288;           // 524288
    float* BC4    = xcT    + 524288;           // 524288
    float* deltaT = BC4    + 524288;           // 524288
    float* sT     = deltaT + 524288;           // 524288
    float* yT     = sT     + 524288;           // 524288
    float* hchain = yT     + 524288;           // 1048576
    float* dsum   = hchain + 1048576;          // 8192
    float* Wdt    = dsum   + 8192;             // 131072
    float* bdt    = Wdt    + 131072;           // 512    (~17.5 MB)

    k_wdt<<<2*4, 256, 0, stream>>>(pl_w, pl_b, dt_w, dt_b, Wdt, bdt);

    for (int l = 0; l < LL; l++) {
        const float* resin = (l == 0) ? x : xres;
        k_front<<<BT/8, 512, 0, stream>>>(
            resin, in_w + (size_t)l*HH*2*EE, in_b + (size_t)l*2*EE,
            norm_w + (size_t)l*HH,
            conv_w + (size_t)l*EE*KK, conv_b + (size_t)l*EE,
            pl_w + (size_t)l*EE*NJ, pl_b + (size_t)l*NJ,
            Wdt + (size_t)l*EE*EE, bdt + (size_t)l*EE,
            zbuf, xcT, BC4, deltaT, sT);
        k_scan_local<<<BB*GG*(EE/4), 128, 0, stream>>>(
            BC4, deltaT, sT, A_log + (size_t)l*EE*HH, yT, hchain, dsum);
        k_scan_fix<<<BB*(GG-1)*(EE/4), 128, 0, stream>>>(
            BC4, deltaT, A_log + (size_t)l*EE*HH, hchain, dsum, yT);
        if (l < LL - 1) {
            k_gate<<<BT/8, 256, 0, stream>>>(
                yT, xcT, zbuf, Dp + (size_t)l*EE,
                out_w + (size_t)l*EE*HH, out_b + (size_t)l*HH, resin, xres);
        } else {
            k_gate_final<<<BT/8, 256, 0, stream>>>(
                yT, xcT, zbuf, Dp + (size_t)l*EE,
                out_w + (size_t)l*EE*HH, out_b + (size_t)l*HH, xres,
                fnw, (float*)d_out);
        }
    }
}